// Round 1
// baseline (278.015 us; speedup 1.0000x reference)
//
#include <hip/hip_runtime.h>
#include <stdint.h>

#define B_      32
#define T_IN_   512
#define N_      543
#define C_      3
#define NEW_T_  426     // int(512/1.2)
#define JF_     53      // max(1, 426//8)
#define NC_     (N_*C_)             // 1629
#define XOUT_   (B_*NEW_T_*NC_)     // 22206528
#define NGROUP_ (XOUT_/4)           // 5551632 (exact)

#define MODE_INT   0
#define MODE_BYTE  1
#define MODE_FLOAT 2

__device__ __forceinline__ bool read_flag(const void* p, int mode, int idx) {
    if (mode == MODE_BYTE)  return ((const uint8_t*)p)[idx] != 0;
    if (mode == MODE_FLOAT) return ((const float*)p)[idx]   != 0.0f;
    return ((const int*)p)[idx] != 0;
}

// One block per batch. Builds per-(b,t): 4 frame indices + 4 weights for pd[b,t],
// jitter value (0 at t=0), and writes the mask output.
__global__ __launch_bounds__(512) void prep_kernel(
    const void* __restrict__ maskp,
    const void* __restrict__ keepp,
    const float* __restrict__ bjit,
    float* __restrict__ out_mask,
    int4*  __restrict__ wsF,
    float4* __restrict__ wsW,
    float* __restrict__ wsJ)
{
    const int b = blockIdx.x;
    const int tid = threadIdx.x;

    __shared__ int flags[6];       // [mask: f32,byte] [keep: f32,byte] (slots 2,1,5,4)
    __shared__ int s_mode_mask, s_mode_keep;
    if (tid < 6) flags[tid] = 0;
    __syncthreads();
    if (tid < 64) {
        uint32_t vm = ((const uint32_t*)maskp)[tid];
        uint32_t vk = ((const uint32_t*)keepp)[tid];
        if (vm == 0x3F800000u)      atomicOr(&flags[2], 1);
        else if (vm > 1u)           atomicOr(&flags[1], 1);
        if (vk == 0x3F800000u)      atomicOr(&flags[5], 1);
        else if (vk > 1u)           atomicOr(&flags[4], 1);
    }
    __syncthreads();
    if (tid == 0) {
        s_mode_mask = flags[2] ? MODE_FLOAT : (flags[1] ? MODE_BYTE : MODE_INT);
        s_mode_keep = flags[5] ? MODE_FLOAT : (flags[4] ? MODE_BYTE : MODE_INT);
    }
    __syncthreads();
    const int mmode = s_mode_mask, kmode = s_mode_keep;

    __shared__ int sk[512];
    __shared__ int ps[512];
    __shared__ int kept[NEW_T_];

    int kv = 0;
    if (tid < NEW_T_) kv = read_flag(keepp, kmode, b*NEW_T_ + tid) ? 1 : 0;
    sk[tid] = (tid < NEW_T_) ? kv : 0;
    ps[tid] = sk[tid];
    __syncthreads();
    // Hillis-Steele inclusive prefix sum over 512 entries
    for (int off = 1; off < 512; off <<= 1) {
        int v = (tid >= off) ? ps[tid - off] : 0;
        __syncthreads();
        ps[tid] += v;
        __syncthreads();
    }
    const int K = ps[NEW_T_ - 1];
    if (tid < NEW_T_ && kv) kept[ps[tid] - 1] = tid;  // kept indices, ascending
    __syncthreads();

    if (tid < NEW_T_) {
        const int t = tid;
        const float RATX = (float)(511.0 / 425.0);   // (T_IN-1)/(NEW_T-1), f32 like jnp
        // y-resample coeff for this t
        float st = (float)t * RATX;
        int i0 = (int)floorf(st);
        if (i0 < 0) i0 = 0; if (i0 > T_IN_ - 2) i0 = T_IN_ - 2;
        float w = st - (float)i0;

        int4 F; float4 W;
        if (kv) {
            F = make_int4(i0, i0 + 1, 0, 1);
            W = make_float4(1.0f - w, w, 0.0f, 0.0f);
        } else {
            float s = ((float)t * (float)(K - 1)) / 425.0f;
            int r0 = (int)floorf(s);
            if (r0 < 0) r0 = 0; if (r0 > K - 2) r0 = K - 2;
            float f = s - (float)r0;
            int j0 = kept[r0], j1 = kept[r0 + 1];
            float s0 = (float)j0 * RATX;
            int a0 = (int)floorf(s0);
            if (a0 < 0) a0 = 0; if (a0 > T_IN_ - 2) a0 = T_IN_ - 2;
            float w0 = s0 - (float)a0;
            float s1 = (float)j1 * RATX;
            int a1 = (int)floorf(s1);
            if (a1 < 0) a1 = 0; if (a1 > T_IN_ - 2) a1 = T_IN_ - 2;
            float w1 = s1 - (float)a1;
            F = make_int4(a0, a0 + 1, a1, a1 + 1);
            W = make_float4((1.0f - f) * (1.0f - w0), (1.0f - f) * w0,
                            f * (1.0f - w1),          f * w1);
        }
        const int bt = b * NEW_T_ + t;
        wsF[bt] = F;
        wsW[bt] = W;

        // jitter: linresample(base_jitter*0.02, NEW_T)
        const float RATJ = (float)(52.0 / 425.0);
        float sj = (float)t * RATJ;
        int ji = (int)floorf(sj);
        if (ji < 0) ji = 0; if (ji > JF_ - 2) ji = JF_ - 2;
        float jf = sj - (float)ji;
        float b0 = bjit[b*JF_ + ji]     * 0.02f;
        float b1 = bjit[b*JF_ + ji + 1] * 0.02f;
        float jv = b0 * (1.0f - jf) + b1 * jf;
        if (t == 0) jv = 0.0f;  // x[:, :1] untouched by jitter
        wsJ[bt] = jv;

        // mask output: mask[:, nidx] & keep
        float mn = (float)t * (float)(512.0 / 426.0);
        int nidx = (int)floorf(mn);
        if (nidx > T_IN_ - 1) nidx = T_IN_ - 1;
        bool mo = read_flag(maskp, mmode, b*T_IN_ + nidx) && (kv != 0);
        out_mask[bt] = mo ? 1.0f : 0.0f;
    }
}

// One thread per 4 consecutive output floats (flat over (b,t,n,c)).
__global__ __launch_bounds__(256) void main_kernel(
    const float* __restrict__ x,
    const float* __restrict__ noise,
    const float* __restrict__ spat,
    const int4*  __restrict__ wsF,
    const float4* __restrict__ wsW,
    const float* __restrict__ wsJ,
    float* __restrict__ out)
{
    uint32_t g = blockIdx.x * 256u + threadIdx.x;
    if (g >= (uint32_t)NGROUP_) return;
    uint32_t flat = g * 4u;
    uint32_t bt = flat / (uint32_t)NC_;
    uint32_t e  = flat - bt * (uint32_t)NC_;

    if (e <= (uint32_t)(NC_ - 4)) {
        // all 4 elements share (b,t)
        uint32_t b = bt / (uint32_t)NEW_T_;
        const float* xb = x + (size_t)b * (T_IN_ * NC_);
        int4  F  = wsF[bt];  float4 W  = wsW[bt];
        uint32_t pbt = bt ? bt - 1u : 0u;
        int4  FP = wsF[pbt]; float4 WP = wsW[pbt];
        float jv = wsJ[bt];

        const float* p0 = xb + (uint32_t)F.x * NC_ + e;
        const float* p1 = xb + (uint32_t)F.y * NC_ + e;
        const float* p2 = xb + (uint32_t)F.z * NC_ + e;
        const float* p3 = xb + (uint32_t)F.w * NC_ + e;
        const float* q0 = xb + (uint32_t)FP.x * NC_ + e;
        const float* q1 = xb + (uint32_t)FP.y * NC_ + e;
        const float* q2 = xb + (uint32_t)FP.z * NC_ + e;
        const float* q3 = xb + (uint32_t)FP.w * NC_ + e;

        float4 nz = *(const float4*)(noise + flat);
        const float* sp = spat + b * NC_ + e;

        float r[4];
        #pragma unroll
        for (int i = 0; i < 4; i++) {
            float a  = W.x  * p0[i] + W.y  * p1[i] + W.z  * p2[i] + W.w  * p3[i];
            float ap = WP.x * q0[i] + WP.y * q1[i] + WP.z * q2[i] + WP.w * q3[i];
            float nzv = (i == 0) ? nz.x : (i == 1) ? nz.y : (i == 2) ? nz.z : nz.w;
            r[i] = a + (a - ap) * jv + nzv * 0.01f + sp[i] * 0.005f;
        }
        float4 o; o.x = r[0]; o.y = r[1]; o.z = r[2]; o.w = r[3];
        *(float4*)(out + flat) = o;
    } else {
        // frame-boundary group: handle each element independently
        #pragma unroll
        for (int i = 0; i < 4; i++) {
            uint32_t fl  = flat + i;
            uint32_t bt2 = fl / (uint32_t)NC_;
            uint32_t e2  = fl - bt2 * (uint32_t)NC_;
            uint32_t b2  = bt2 / (uint32_t)NEW_T_;
            const float* xb = x + (size_t)b2 * (T_IN_ * NC_);
            int4  F  = wsF[bt2];  float4 W  = wsW[bt2];
            uint32_t pbt = bt2 ? bt2 - 1u : 0u;
            int4  FP = wsF[pbt];  float4 WP = wsW[pbt];
            float jv = wsJ[bt2];
            float a  = W.x  * xb[(uint32_t)F.x  * NC_ + e2] + W.y  * xb[(uint32_t)F.y  * NC_ + e2]
                     + W.z  * xb[(uint32_t)F.z  * NC_ + e2] + W.w  * xb[(uint32_t)F.w  * NC_ + e2];
            float ap = WP.x * xb[(uint32_t)FP.x * NC_ + e2] + WP.y * xb[(uint32_t)FP.y * NC_ + e2]
                     + WP.z * xb[(uint32_t)FP.z * NC_ + e2] + WP.w * xb[(uint32_t)FP.w * NC_ + e2];
            out[fl] = a + (a - ap) * jv + noise[fl] * 0.01f + spat[b2 * NC_ + e2] * 0.005f;
        }
    }
}

extern "C" void kernel_launch(void* const* d_in, const int* in_sizes, int n_in,
                              void* d_out, int out_size, void* d_ws, size_t ws_size,
                              hipStream_t stream) {
    const float* x    = (const float*)d_in[0];
    const void*  mask = d_in[1];
    const void*  keep = d_in[2];
    const float* bjit = (const float*)d_in[3];
    const float* noise = (const float*)d_in[4];
    const float* spat  = (const float*)d_in[5];
    float* out = (float*)d_out;

    // workspace carve
    char* ws = (char*)d_ws;
    int4*   wsF = (int4*)ws;                           // 13632*16 = 218112 B
    float4* wsW = (float4*)(ws + 218112);              // 218112 B
    float*  wsJ = (float*)(ws + 436224);               // 54528 B

    prep_kernel<<<B_, 512, 0, stream>>>(mask, keep, bjit,
                                        out + XOUT_, wsF, wsW, wsJ);
    const int nblk = (NGROUP_ + 255) / 256;
    main_kernel<<<nblk, 256, 0, stream>>>(x, noise, spat, wsF, wsW, wsJ, out);
}